// Round 20
// baseline (361.075 us; speedup 1.0000x reference)
//
#include <hip/hip_runtime.h>
#include <cstdint>
#include <cstddef>

#define NPTS 2048
#define NBAT 8

typedef unsigned long long ull;
typedef __attribute__((ext_vector_type(8))) short bf16x8;
typedef __attribute__((ext_vector_type(4))) float f32x4;

__device__ __forceinline__ float4 ld4(const float* p){ return *reinterpret_cast<const float4*>(p); }
__device__ __forceinline__ void st4(float* p, float4 v){ *reinterpret_cast<float4*>(p) = v; }
__device__ __forceinline__ unsigned short f2bf(float f){
    unsigned int u = __float_as_uint(f);
    u += 0x7FFFu + ((u >> 16) & 1u);
    return (unsigned short)(u >> 16);
}
__device__ __forceinline__ float bf2f(unsigned short h){
    return __uint_as_float(((unsigned int)h) << 16);
}

// LDS-only barrier: waits local ds ops, leaves global loads (vmcnt) in flight.
#define BAR_LDS() do { asm volatile("s_waitcnt lgkmcnt(0)" ::: "memory"); \
                       __builtin_amdgcn_s_barrier(); } while (0)

__device__ __forceinline__ float blk_red_sum(float v, float* red){
    #pragma unroll
    for (int o = 32; o > 0; o >>= 1) v += __shfl_xor(v, o, 64);
    int wid = threadIdx.x >> 6;
    if ((threadIdx.x & 63) == 0) red[wid] = v;
    __syncthreads();
    v = red[0] + red[1] + red[2] + red[3];
    __syncthreads();
    return v;
}

// ---------------------------------------------------------------------------
// MFMA linear: out[b,d,n] = sum_c W[d,c]*X[b,c,n] (+bias)
// MODE: 0=fp32 out, 1=bf16 out.
// STATS (MODE 0): per-WG channel partials -> part[c*512 + b*64 + bx]; no atomics.
// ---------------------------------------------------------------------------
template<int CIN, int COUT, int TD, int TN, int MODE, bool BIAS, bool STATS>
__global__ __launch_bounds__(256) void lin_mfma_kernel(
        const float* __restrict__ W, const float* __restrict__ X,
        const float* __restrict__ bias, void* __restrict__ outv,
        float* __restrict__ pout)
{
    constexpr int WD  = TD / 16;
    constexpr int NPW = TN * WD / 4;
    constexpr int FB  = NPW / 16;
    constexpr int KS  = CIN / 32;
    __shared__ unsigned short Xhi[TN * CIN];
    __shared__ unsigned short Xlo[TN * CIN];
    const int tid = threadIdx.x;
    const int lane = tid & 63;
    const int w = tid >> 6;
    const int g = lane >> 4;
    const int l15 = lane & 15;
    const int b = blockIdx.z;
    const int d0 = blockIdx.y * TD;
    const int n0 = blockIdx.x * TN;
    const int dw = (w % WD) * 16;
    const int nw = (w / WD) * NPW;

    bf16x8 Whi[KS], Wlo[KS];
    {
        const int d = d0 + dw + l15;
        #pragma unroll
        for (int ks = 0; ks < KS; ++ks) {
            float4 a = ld4(&W[(size_t)d * CIN + ks * 32 + g * 8]);
            float4 bq = ld4(&W[(size_t)d * CIN + ks * 32 + g * 8 + 4]);
            float vv[8] = {a.x, a.y, a.z, a.w, bq.x, bq.y, bq.z, bq.w};
            bf16x8 h8, l8;
            #pragma unroll
            for (int e = 0; e < 8; ++e) {
                unsigned short hh = f2bf(vv[e]);
                h8[e] = (short)hh;
                l8[e] = (short)f2bf(vv[e] - bf2f(hh));
            }
            Whi[ks] = h8; Wlo[ks] = l8;
        }
    }
    constexpr int TN4 = TN / 4;
    constexpr int NF = (TN * CIN) / 1024;
    #pragma unroll
    for (int f = 0; f < NF; ++f) {
        int idx = tid + 256 * f;
        int c = idx / TN4;
        int n = (idx % TN4) * 4;
        float4 xv = ld4(&X[((size_t)(b * CIN + c)) * NPTS + n0 + n]);
        float vv[4] = {xv.x, xv.y, xv.z, xv.w};
        #pragma unroll
        for (int j2 = 0; j2 < 4; ++j2) {
            int nn = n + j2;
            int cp = (c + nn * 8) & (CIN - 1);
            unsigned short hh = f2bf(vv[j2]);
            Xhi[nn * CIN + cp] = hh;
            Xlo[nn * CIN + cp] = f2bf(vv[j2] - bf2f(hh));
        }
    }
    __syncthreads();

    f32x4 acc[FB];
    #pragma unroll
    for (int fb = 0; fb < FB; ++fb) acc[fb] = (f32x4){0.f, 0.f, 0.f, 0.f};
    #pragma unroll
    for (int ks = 0; ks < KS; ++ks) {
        #pragma unroll
        for (int fb = 0; fb < FB; ++fb) {
            int n = nw + fb * 16 + l15;
            int cp = (ks * 32 + g * 8 + n * 8) & (CIN - 1);
            bf16x8 xh = *reinterpret_cast<bf16x8*>(&Xhi[n * CIN + cp]);
            bf16x8 xl = *reinterpret_cast<bf16x8*>(&Xlo[n * CIN + cp]);
            acc[fb] = __builtin_amdgcn_mfma_f32_16x16x32_bf16(Wlo[ks], xh, acc[fb], 0, 0, 0);
            acc[fb] = __builtin_amdgcn_mfma_f32_16x16x32_bf16(Whi[ks], xl, acc[fb], 0, 0, 0);
            acc[fb] = __builtin_amdgcn_mfma_f32_16x16x32_bf16(Whi[ks], xh, acc[fb], 0, 0, 0);
        }
    }
    const int dbase = d0 + dw + g * 4;
    float bb[4] = {0.f, 0.f, 0.f, 0.f};
    if (BIAS) {
        float4 b4 = ld4(&bias[dbase]);
        bb[0] = b4.x; bb[1] = b4.y; bb[2] = b4.z; bb[3] = b4.w;
    }
    float s1[4] = {0.f, 0.f, 0.f, 0.f};
    float s2[4] = {0.f, 0.f, 0.f, 0.f};
    #pragma unroll
    for (int fb = 0; fb < FB; ++fb) {
        int ncol = n0 + nw + fb * 16 + l15;
        if (MODE == 1) {
            unsigned short* ob = (unsigned short*)outv;
            #pragma unroll
            for (int r = 0; r < 4; ++r)
                ob[((size_t)(b * COUT + dbase + r)) * NPTS + ncol] = f2bf(acc[fb][r] + bb[r]);
        } else {
            float* ob = (float*)outv;
            #pragma unroll
            for (int r = 0; r < 4; ++r) {
                float val = acc[fb][r] + bb[r];
                ob[((size_t)(b * COUT + dbase + r)) * NPTS + ncol] = val;
                if (STATS) { s1[r] += val; s2[r] += val * val; }
            }
        }
    }
    if (STATS && MODE == 0) {
        #pragma unroll
        for (int r = 0; r < 4; ++r) {
            float a1 = s1[r], a2 = s2[r];
            a1 += __shfl_xor(a1, 1, 64);  a2 += __shfl_xor(a2, 1, 64);
            a1 += __shfl_xor(a1, 2, 64);  a2 += __shfl_xor(a2, 2, 64);
            a1 += __shfl_xor(a1, 4, 64);  a2 += __shfl_xor(a2, 4, 64);
            a1 += __shfl_xor(a1, 8, 64);  a2 += __shfl_xor(a2, 8, 64);
            if (l15 == 0) {
                int c = dbase + r;
                int slot = b * 64 + blockIdx.x;
                pout[(size_t)c * 512 + slot] = a1;
                pout[(size_t)(128 + c) * 512 + slot] = a2;
            }
        }
    }
}

// ---------------------------------------------------------------------------
// Fused q/k + v projection: one pass over h.
// ---------------------------------------------------------------------------
__global__ __launch_bounds__(256) void qkv_kernel(
        const float* __restrict__ Wqk, const float* __restrict__ Wv,
        const float* __restrict__ X, const float* __restrict__ bv,
        unsigned short* __restrict__ vb,
        unsigned short* __restrict__ qh, unsigned short* __restrict__ ql)
{
    __shared__ unsigned short Xhi[32 * 128];
    __shared__ unsigned short Xlo[32 * 128];
    const int tid = threadIdx.x;
    const int lane = tid & 63;
    const int w = tid >> 6;          // 0..3
    const int g = lane >> 4;
    const int l15 = lane & 15;
    const int b = blockIdx.z;
    const int gy = blockIdx.y;
    const int d0 = gy * 64;
    const int n0 = blockIdx.x * 32;
    const int dw = w * 16;
    const bool doqk = (gy == 0) && (w < 2);

    bf16x8 Vhi[4], Vlo[4];
    {
        const int d = d0 + dw + l15;
        #pragma unroll
        for (int ks = 0; ks < 4; ++ks) {
            float4 a = ld4(&Wv[(size_t)d * 128 + ks * 32 + g * 8]);
            float4 bq = ld4(&Wv[(size_t)d * 128 + ks * 32 + g * 8 + 4]);
            float vv[8] = {a.x, a.y, a.z, a.w, bq.x, bq.y, bq.z, bq.w};
            bf16x8 h8, l8;
            #pragma unroll
            for (int e = 0; e < 8; ++e) {
                unsigned short hh = f2bf(vv[e]);
                h8[e] = (short)hh;
                l8[e] = (short)f2bf(vv[e] - bf2f(hh));
            }
            Vhi[ks] = h8; Vlo[ks] = l8;
        }
    }
    bf16x8 Qhi[4], Qlo[4];
    if (doqk) {
        const int d = dw + l15;
        #pragma unroll
        for (int ks = 0; ks < 4; ++ks) {
            float4 a = ld4(&Wqk[(size_t)d * 128 + ks * 32 + g * 8]);
            float4 bq = ld4(&Wqk[(size_t)d * 128 + ks * 32 + g * 8 + 4]);
            float vv[8] = {a.x, a.y, a.z, a.w, bq.x, bq.y, bq.z, bq.w};
            bf16x8 h8, l8;
            #pragma unroll
            for (int e = 0; e < 8; ++e) {
                unsigned short hh = f2bf(vv[e]);
                h8[e] = (short)hh;
                l8[e] = (short)f2bf(vv[e] - bf2f(hh));
            }
            Qhi[ks] = h8; Qlo[ks] = l8;
        }
    }
    #pragma unroll
    for (int f = 0; f < 4; ++f) {
        int idx = tid + 256 * f;
        int c = idx / 8;
        int n = (idx % 8) * 4;
        float4 xv = ld4(&X[((size_t)(b * 128 + c)) * NPTS + n0 + n]);
        float vv[4] = {xv.x, xv.y, xv.z, xv.w};
        #pragma unroll
        for (int j2 = 0; j2 < 4; ++j2) {
            int nn = n + j2;
            int cp = (c + nn * 8) & 127;
            unsigned short hh = f2bf(vv[j2]);
            Xhi[nn * 128 + cp] = hh;
            Xlo[nn * 128 + cp] = f2bf(vv[j2] - bf2f(hh));
        }
    }
    __syncthreads();

    f32x4 acc[2];
    acc[0] = (f32x4){0.f, 0.f, 0.f, 0.f};
    acc[1] = (f32x4){0.f, 0.f, 0.f, 0.f};
    #pragma unroll
    for (int ks = 0; ks < 4; ++ks) {
        #pragma unroll
        for (int fb = 0; fb < 2; ++fb) {
            int n = fb * 16 + l15;
            int cp = (ks * 32 + g * 8 + n * 8) & 127;
            bf16x8 xh = *reinterpret_cast<bf16x8*>(&Xhi[n * 128 + cp]);
            bf16x8 xl = *reinterpret_cast<bf16x8*>(&Xlo[n * 128 + cp]);
            acc[fb] = __builtin_amdgcn_mfma_f32_16x16x32_bf16(Vlo[ks], xh, acc[fb], 0, 0, 0);
            acc[fb] = __builtin_amdgcn_mfma_f32_16x16x32_bf16(Vhi[ks], xl, acc[fb], 0, 0, 0);
            acc[fb] = __builtin_amdgcn_mfma_f32_16x16x32_bf16(Vhi[ks], xh, acc[fb], 0, 0, 0);
        }
    }
    {
        const int dbase = d0 + dw + g * 4;
        float4 b4 = ld4(&bv[dbase]);
        float bb[4] = {b4.x, b4.y, b4.z, b4.w};
        #pragma unroll
        for (int fb = 0; fb < 2; ++fb) {
            int ncol = n0 + fb * 16 + l15;
            #pragma unroll
            for (int r = 0; r < 4; ++r)
                vb[((size_t)(b * 128 + dbase + r)) * NPTS + ncol] = f2bf(acc[fb][r] + bb[r]);
        }
    }
    if (doqk) {
        f32x4 accq[2];
        accq[0] = (f32x4){0.f, 0.f, 0.f, 0.f};
        accq[1] = (f32x4){0.f, 0.f, 0.f, 0.f};
        #pragma unroll
        for (int ks = 0; ks < 4; ++ks) {
            #pragma unroll
            for (int fb = 0; fb < 2; ++fb) {
                int n = fb * 16 + l15;
                int cp = (ks * 32 + g * 8 + n * 8) & 127;
                bf16x8 xh = *reinterpret_cast<bf16x8*>(&Xhi[n * 128 + cp]);
                bf16x8 xl = *reinterpret_cast<bf16x8*>(&Xlo[n * 128 + cp]);
                accq[fb] = __builtin_amdgcn_mfma_f32_16x16x32_bf16(Qlo[ks], xh, accq[fb], 0, 0, 0);
                accq[fb] = __builtin_amdgcn_mfma_f32_16x16x32_bf16(Qhi[ks], xl, accq[fb], 0, 0, 0);
                accq[fb] = __builtin_amdgcn_mfma_f32_16x16x32_bf16(Qhi[ks], xh, accq[fb], 0, 0, 0);
            }
        }
        const int dq = dw + g * 4;
        #pragma unroll
        for (int fb = 0; fb < 2; ++fb) {
            int ncol = n0 + fb * 16 + l15;
            ushort4 hh, ll;
            float q0 = accq[fb][0], q1 = accq[fb][1], q2 = accq[fb][2], q3 = accq[fb][3];
            hh.x = f2bf(q0); ll.x = f2bf(q0 - bf2f(hh.x));
            hh.y = f2bf(q1); ll.y = f2bf(q1 - bf2f(hh.y));
            hh.z = f2bf(q2); ll.z = f2bf(q2 - bf2f(hh.z));
            hh.w = f2bf(q3); ll.w = f2bf(q3 - bf2f(hh.w));
            *reinterpret_cast<ushort4*>(&qh[((size_t)b * NPTS + ncol) * 32 + dq]) = hh;
            *reinterpret_cast<ushort4*>(&ql[((size_t)b * NPTS + ncol) * 32 + dq]) = ll;
        }
    }
}

// finalize: reduce 512 coalesced partials per channel -> stats
__global__ __launch_bounds__(256) void bn_finalize_kernel(
        const float* __restrict__ part, float* __restrict__ stats, int C)
{
    __shared__ float red[4];
    const int c = blockIdx.x;
    const int tid = threadIdx.x;
    float s  = part[(size_t)c * 512 + tid] + part[(size_t)c * 512 + 256 + tid];
    float s2 = part[(size_t)(128 + c) * 512 + tid] + part[(size_t)(128 + c) * 512 + 256 + tid];
    s  = blk_red_sum(s, red);
    s2 = blk_red_sum(s2, red);
    if (tid == 0) {
        const float invn = 1.f / (NBAT * NPTS);
        float mean = s * invn;
        stats[c] = mean;
        stats[C + c] = rsqrtf(s2 * invn - mean * mean + 1e-5f);
    }
}

// row softmax stats; 1-D grid 1024, b = id&7 (XCD-aligned), i0 = (id>>3)*16
__global__ __launch_bounds__(256) void rowstats_fused_kernel(
        const unsigned short* __restrict__ qThi, const unsigned short* __restrict__ qTlo,
        float* __restrict__ rowm, float* __restrict__ rowinv)
{
    __shared__ float pm[4][16];
    __shared__ float ps[4][16];
    const int lane = threadIdx.x & 63;
    const int w = threadIdx.x >> 6;
    const int b = blockIdx.x & 7;
    const int i0 = (blockIdx.x >> 3) * 16;
    const int g = lane >> 4;
    const int l15 = lane & 15;
    const int iR = i0 + l15;
    const bf16x8 bhi = *reinterpret_cast<const bf16x8*>(&qThi[((size_t)b * NPTS + iR) * 32 + g * 8]);
    const bf16x8 blo = *reinterpret_cast<const bf16x8*>(&qTlo[((size_t)b * NPTS + iR) * 32 + g * 8]);
    float m = -1e30f, s = 0.f;
    for (int t = w * 32; t < w * 32 + 32; ++t) {
        int jr = t * 16 + l15;
        const bf16x8 ahi = *reinterpret_cast<const bf16x8*>(&qThi[((size_t)b * NPTS + jr) * 32 + g * 8]);
        const bf16x8 alo = *reinterpret_cast<const bf16x8*>(&qTlo[((size_t)b * NPTS + jr) * 32 + g * 8]);
        f32x4 e4 = {0.f, 0.f, 0.f, 0.f};
        e4 = __builtin_amdgcn_mfma_f32_16x16x32_bf16(alo, bhi, e4, 0, 0, 0);
        e4 = __builtin_amdgcn_mfma_f32_16x16x32_bf16(ahi, blo, e4, 0, 0, 0);
        e4 = __builtin_amdgcn_mfma_f32_16x16x32_bf16(ahi, bhi, e4, 0, 0, 0);
        float tm = fmaxf(fmaxf(e4[0], e4[1]), fmaxf(e4[2], e4[3]));
        float nm = fmaxf(m, tm);
        s *= __expf(m - nm);
        m = nm;
        s += __expf(e4[0] - m) + __expf(e4[1] - m) + __expf(e4[2] - m) + __expf(e4[3] - m);
    }
    #pragma unroll
    for (int o = 16; o <= 32; o <<= 1) {
        float om = __shfl_xor(m, o, 64);
        float os = __shfl_xor(s, o, 64);
        float nm = fmaxf(m, om);
        s = s * __expf(m - nm) + os * __expf(om - nm);
        m = nm;
    }
    if (lane < 16) { pm[w][l15] = m; ps[w][l15] = s; }
    __syncthreads();
    if (threadIdx.x < 16) {
        float m0 = pm[0][threadIdx.x], m1 = pm[1][threadIdx.x];
        float m2 = pm[2][threadIdx.x], m3 = pm[3][threadIdx.x];
        float mf = fmaxf(fmaxf(m0, m1), fmaxf(m2, m3));
        float sf = ps[0][threadIdx.x] * __expf(m0 - mf)
                 + ps[1][threadIdx.x] * __expf(m1 - mf)
                 + ps[2][threadIdx.x] * __expf(m2 - mf)
                 + ps[3][threadIdx.x] * __expf(m3 - mf);
        rowm[(size_t)b * NPTS + i0 + threadIdx.x] = mf;
        rowinv[(size_t)b * NPTS + i0 + threadIdx.x] = 1.f / sf;
    }
}

// Fused attention; 1-D grid 512, b = id&7 (XCD-aligned), j0 = (id>>3)*32.
// Linear prefetch + padded buffers; s_setprio(1) around MFMA clusters (T5).
__global__ __launch_bounds__(512) void attn_fused_kernel(
        const unsigned short* __restrict__ qThi, const unsigned short* __restrict__ qTlo,
        const unsigned short* __restrict__ V,
        const float* __restrict__ rowm, const float* __restrict__ rowinv,
        const float* __restrict__ H, float* __restrict__ T)
{
    __shared__ unsigned short Alds[2][128 * 64];
    __shared__ unsigned short Blds[2][32 * 64];
    __shared__ float cparts[8][16];
    const int tid = threadIdx.x;
    const int b  = blockIdx.x & 7;
    const int j0 = (blockIdx.x >> 3) * 32;
    const int lane = tid & 63;
    const int w = tid >> 6;
    const int g = lane >> 4;
    const int l15 = lane & 15;
    const int jsub = w & 1;
    const int tE = w >> 1;
    const int jl = jsub * 16 + l15;
    const int cb = (w >> 1) * 32;
    const int jb = jsub * 16;
    const int vc = tid >> 3, vslot = tid & 7;
    const int vc1 = (tid + 512) >> 3, vslot1 = (tid + 512) & 7;
    const bf16x8 bhi = *reinterpret_cast<const bf16x8*>(&qThi[((size_t)b * NPTS + j0 + jl) * 32 + g * 8]);
    const bf16x8 blo = *reinterpret_cast<const bf16x8*>(&qTlo[((size_t)b * NPTS + j0 + jl) * 32 + g * 8]);
    f32x4 acc[2];
    acc[0] = (f32x4){0.f, 0.f, 0.f, 0.f};
    acc[1] = (f32x4){0.f, 0.f, 0.f, 0.f};
    float csum = 0.f;

    // linear prefetch pointers (advance 64 elements per step)
    const unsigned short* pv0 = V + ((size_t)(b * 128 + vc)) * NPTS + vslot * 8;
    const unsigned short* pv1 = V + ((size_t)(b * 128 + vc1)) * NPTS + vslot1 * 8;
    const unsigned short* pqh = qThi + ((size_t)b * NPTS + tE * 16 + l15) * 32 + g * 8;
    const unsigned short* pql = qTlo + ((size_t)b * NPTS + tE * 16 + l15) * 32 + g * 8;
    const float* prm = rowm + (size_t)b * NPTS + tE * 16 + g * 4;
    const float* pri = rowinv + (size_t)b * NPTS + tE * 16 + g * 4;

    float4 vreg0 = ld4((const float*)pv0);
    float4 vreg1 = ld4((const float*)pv1);
    bf16x8 pahi = *reinterpret_cast<const bf16x8*>(pqh);
    bf16x8 palo = *reinterpret_cast<const bf16x8*>(pql);
    float4 pmv = ld4(prm);
    float4 psv = ld4(pri);

    int p = 0;
    for (int i0 = 0; i0 < NPTS; i0 += 64) {
        // commit prefetched V tile to Alds[p]
        {
            int sl = vslot ^ (vc & 7);
            *reinterpret_cast<float4*>(&Alds[p][vc * 64 + sl * 8]) = vreg0;
            sl = vslot1 ^ (vc1 & 7);
            *reinterpret_cast<float4*>(&Alds[p][vc1 * 64 + sl * 8]) = vreg1;
        }
        // e-compute from prefetched qT frags -> Blds[p]
        {
            f32x4 e4 = {0.f, 0.f, 0.f, 0.f};
            __builtin_amdgcn_s_setprio(1);
            e4 = __builtin_amdgcn_mfma_f32_16x16x32_bf16(palo, bhi, e4, 0, 0, 0);
            e4 = __builtin_amdgcn_mfma_f32_16x16x32_bf16(pahi, blo, e4, 0, 0, 0);
            e4 = __builtin_amdgcn_mfma_f32_16x16x32_bf16(pahi, bhi, e4, 0, 0, 0);
            __builtin_amdgcn_s_setprio(0);
            float p0 = __expf(e4[0] - pmv.x) * psv.x;
            float p1 = __expf(e4[1] - pmv.y) * psv.y;
            float p2 = __expf(e4[2] - pmv.z) * psv.z;
            float p3 = __expf(e4[3] - pmv.w) * psv.w;
            csum += p0 + p1 + p2 + p3;
            int il = tE * 16 + g * 4;
            int sl = (il >> 3) ^ (jl & 7);
            ull pk = (ull)f2bf(p0) | ((ull)f2bf(p1) << 16) |
                     ((ull)f2bf(p2) << 32) | ((ull)f2bf(p3) << 48);
            *reinterpret_cast<ull*>(&Blds[p][jl * 64 + sl * 8 + (il & 7)]) = pk;
        }
        // prefetch next step (linear advance; final prefetch reads pad garbage)
        {
            pv0 += 64; pv1 += 64;
            pqh += 64 * 32; pql += 64 * 32;
            prm += 64; pri += 64;
            vreg0 = ld4((const float*)pv0);
            vreg1 = ld4((const float*)pv1);
            pahi = *reinterpret_cast<const bf16x8*>(pqh);
            palo = *reinterpret_cast<const bf16x8*>(pql);
            pmv = ld4(prm);
            psv = ld4(pri);
        }
        BAR_LDS();
        // PV: 32c x 16j slice, K=64
        __builtin_amdgcn_s_setprio(1);
        #pragma unroll
        for (int ks = 0; ks < 2; ++ks) {
            int j = jb + l15;
            int slb = (ks * 4 + g) ^ (j & 7);
            bf16x8 bfr = *reinterpret_cast<bf16x8*>(&Blds[p][j * 64 + slb * 8]);
            #pragma unroll
            for (int fa = 0; fa < 2; ++fa) {
                int c = cb + fa * 16 + l15;
                int sla = (ks * 4 + g) ^ (c & 7);
                bf16x8 afr = *reinterpret_cast<bf16x8*>(&Alds[p][c * 64 + sla * 8]);
                acc[fa] = __builtin_amdgcn_mfma_f32_16x16x32_bf16(afr, bfr, acc[fa], 0, 0, 0);
            }
        }
        __builtin_amdgcn_s_setprio(0);
        p ^= 1;
    }
    csum += __shfl_xor(csum, 16, 64);
    csum += __shfl_xor(csum, 32, 64);
    if (lane < 16) cparts[w][l15] = csum;
    __syncthreads();
    float cs = cparts[jsub][l15] + cparts[jsub + 2][l15]
             + cparts[jsub + 4][l15] + cparts[jsub + 6][l15];
    float inv = 1.f / (1e-9f + cs);
    int jg_ = j0 + jb + l15;
    #pragma unroll
    for (int fa = 0; fa < 2; ++fa) {
        #pragma unroll
        for (int r = 0; r < 4; ++r) {
            int c = cb + fa * 16 + g * 4 + r;
            size_t base = ((size_t)(b * 128 + c)) * NPTS + jg_;
            T[base] = H[base] - acc[fa][r] * inv;
        }
    }
}

__global__ __launch_bounds__(256) void bn_apply_kernel(const float* __restrict__ X,
        const float* __restrict__ g, const float* __restrict__ beta,
        const float* __restrict__ stats, int C, float* __restrict__ out)
{
    const int bc = blockIdx.y;
    const int c = bc % C;
    const int n = blockIdx.x * 1024 + threadIdx.x * 4;
    const float mean = stats[c], is = stats[C + c];
    const float ga = g[c] * is;
    const float be = beta[c] - mean * ga;
    float4 v = ld4(&X[(size_t)bc * NPTS + n]);
    float4 o;
    o.x = fmaxf(fmaf(ga, v.x, be), 0.f);
    o.y = fmaxf(fmaf(ga, v.y, be), 0.f);
    o.z = fmaxf(fmaf(ga, v.z, be), 0.f);
    o.w = fmaxf(fmaf(ga, v.w, be), 0.f);
    st4(&out[(size_t)bc * NPTS + n], o);
}

__global__ __launch_bounds__(256) void bn_res_kernel(const float* __restrict__ Y,
        const float* __restrict__ g, const float* __restrict__ beta,
        const float* __restrict__ stats, float* __restrict__ H,
        float* __restrict__ out, int blk)
{
    const int bc = blockIdx.y;
    const int c = bc & 127;
    const int b = bc >> 7;
    const int n = blockIdx.x * 1024 + threadIdx.x * 4;
    const float mean = stats[c], is = stats[128 + c];
    const float ga = g[c] * is;
    const float be = beta[c] - mean * ga;
    float4 yv = ld4(&Y[(size_t)bc * NPTS + n]);
    float4 hv = ld4(&H[(size_t)bc * NPTS + n]);
    float4 o;
    o.x = hv.x + fmaxf(fmaf(ga, yv.x, be), 0.f);
    o.y = hv.y + fmaxf(fmaf(ga, yv.y, be), 0.f);
    o.z = hv.z + fmaxf(fmaf(ga, yv.z, be), 0.f);
    o.w = hv.w + fmaxf(fmaf(ga, yv.w, be), 0.f);
    st4(&H[(size_t)bc * NPTS + n], o);
    st4(&out[((size_t)(b * 512 + blk * 128 + c)) * NPTS + n], o);
}

extern "C" void kernel_launch(void* const* d_in, const int* in_sizes, int n_in,
                              void* d_out, int out_size, void* d_ws, size_t ws_size,
                              hipStream_t stream)
{
    const float* x   = (const float*)d_in[0];
    const float* W1  = (const float*)d_in[1];
    const float* g1  = (const float*)d_in[2];
    const float* b1  = (const float*)d_in[3];
    const float* W2  = (const float*)d_in[4];
    const float* g2  = (const float*)d_in[5];
    const float* b2  = (const float*)d_in[6];
    const float* Wqk = (const float*)d_in[7];
    const float* Wv  = (const float*)d_in[8];
    const float* bv  = (const float*)d_in[9];
    const float* Wt  = (const float*)d_in[10];
    const float* bt  = (const float*)d_in[11];
    const float* gn  = (const float*)d_in[12];
    const float* bnb = (const float*)d_in[13];
    float* out = (float*)d_out;

    float* ws = (float*)d_ws;
    size_t off = 0;
    auto alloc = [&](size_t n) { float* p = ws + off; off += n; return p; };
    float* h      = alloc((size_t)NBAT * 128 * NPTS);
    float* t      = alloc((size_t)NBAT * 128 * NPTS);
    float* y      = alloc((size_t)NBAT * 128 * NPTS);
    float* part   = alloc((size_t)2 * 128 * 512);
    float* stats  = alloc(256);
    float* rowm   = alloc((size_t)NBAT * NPTS + 128);   // +pad for linear prefetch
    float* rowinv = alloc((size_t)NBAT * NPTS + 128);   // +pad
    unsigned short* vb   = (unsigned short*)alloc((size_t)NBAT * 128 * NPTS / 2 + 2048);
    unsigned short* qThi = (unsigned short*)alloc((size_t)NBAT * NPTS * 32 / 2 + 2048);
    unsigned short* qTlo = (unsigned short*)alloc((size_t)NBAT * NPTS * 32 / 2 + 2048);

    // stem: h = relu(bn(W2 @ relu(bn(W1 @ x))))
    lin_mfma_kernel<64, 64, 64, 32, 0, false, true><<<dim3(64, 1, NBAT), 256, 0, stream>>>(
        W1, x, nullptr, y, part);
    bn_finalize_kernel<<<64, 256, 0, stream>>>(part, stats, 64);
    bn_apply_kernel<<<dim3(2, NBAT * 64), 256, 0, stream>>>(y, g1, b1, stats, 64, t);
    lin_mfma_kernel<64, 128, 64, 32, 0, false, true><<<dim3(64, 2, NBAT), 256, 0, stream>>>(
        W2, t, nullptr, y, part);
    bn_finalize_kernel<<<128, 256, 0, stream>>>(part, stats, 128);
    bn_apply_kernel<<<dim3(2, NBAT * 128), 256, 0, stream>>>(y, g2, b2, stats, 128, h);

    for (int blk = 0; blk < 4; ++blk) {
        qkv_kernel<<<dim3(64, 2, NBAT), 256, 0, stream>>>(
            Wqk + (size_t)blk * 32 * 128, Wv + (size_t)blk * 128 * 128,
            h, bv + blk * 128, vb, qThi, qTlo);
        rowstats_fused_kernel<<<1024, 256, 0, stream>>>(qThi, qTlo, rowm, rowinv);
        attn_fused_kernel<<<512, 512, 0, stream>>>(
            qThi, qTlo, vb, rowm, rowinv, h, t);
        lin_mfma_kernel<128, 128, 64, 32, 0, true, true><<<dim3(64, 2, NBAT), 256, 0, stream>>>(
            Wt + (size_t)blk * 128 * 128, t, bt + blk * 128, y, part);
        bn_finalize_kernel<<<128, 256, 0, stream>>>(part, stats, 128);
        bn_res_kernel<<<dim3(2, NBAT * 128), 256, 0, stream>>>(
            y, gn + blk * 128, bnb + blk * 128, stats, h, out, blk);
    }
}

// Round 21
// 356.670 us; speedup vs baseline: 1.0123x; 1.0123x over previous
//
#include <hip/hip_runtime.h>
#include <cstdint>
#include <cstddef>

#define NPTS 2048
#define NBAT 8

typedef unsigned long long ull;
typedef __attribute__((ext_vector_type(8))) short bf16x8;
typedef __attribute__((ext_vector_type(4))) float f32x4;

__device__ __forceinline__ float4 ld4(const float* p){ return *reinterpret_cast<const float4*>(p); }
__device__ __forceinline__ void st4(float* p, float4 v){ *reinterpret_cast<float4*>(p) = v; }
__device__ __forceinline__ unsigned short f2bf(float f){
    unsigned int u = __float_as_uint(f);
    u += 0x7FFFu + ((u >> 16) & 1u);
    return (unsigned short)(u >> 16);
}
__device__ __forceinline__ float bf2f(unsigned short h){
    return __uint_as_float(((unsigned int)h) << 16);
}

// LDS-only barrier: waits local ds ops, leaves global loads (vmcnt) in flight.
#define BAR_LDS() do { asm volatile("s_waitcnt lgkmcnt(0)" ::: "memory"); \
                       __builtin_amdgcn_s_barrier(); } while (0)

__device__ __forceinline__ float blk_red_sum(float v, float* red){
    #pragma unroll
    for (int o = 32; o > 0; o >>= 1) v += __shfl_xor(v, o, 64);
    int wid = threadIdx.x >> 6;
    if ((threadIdx.x & 63) == 0) red[wid] = v;
    __syncthreads();
    v = red[0] + red[1] + red[2] + red[3];
    __syncthreads();
    return v;
}

// ---------------------------------------------------------------------------
// MFMA linear: out[b,d,n] = sum_c W[d,c]*X[b,c,n] (+bias)
// MODE: 0=fp32 out, 1=bf16 out.
// STATS (MODE 0): per-WG channel partials -> part[c*512 + b*64 + bx]; no atomics.
// ---------------------------------------------------------------------------
template<int CIN, int COUT, int TD, int TN, int MODE, bool BIAS, bool STATS>
__global__ __launch_bounds__(256) void lin_mfma_kernel(
        const float* __restrict__ W, const float* __restrict__ X,
        const float* __restrict__ bias, void* __restrict__ outv,
        float* __restrict__ pout)
{
    constexpr int WD  = TD / 16;
    constexpr int NPW = TN * WD / 4;
    constexpr int FB  = NPW / 16;
    constexpr int KS  = CIN / 32;
    __shared__ unsigned short Xhi[TN * CIN];
    __shared__ unsigned short Xlo[TN * CIN];
    const int tid = threadIdx.x;
    const int lane = tid & 63;
    const int w = tid >> 6;
    const int g = lane >> 4;
    const int l15 = lane & 15;
    const int b = blockIdx.z;
    const int d0 = blockIdx.y * TD;
    const int n0 = blockIdx.x * TN;
    const int dw = (w % WD) * 16;
    const int nw = (w / WD) * NPW;

    bf16x8 Whi[KS], Wlo[KS];
    {
        const int d = d0 + dw + l15;
        #pragma unroll
        for (int ks = 0; ks < KS; ++ks) {
            float4 a = ld4(&W[(size_t)d * CIN + ks * 32 + g * 8]);
            float4 bq = ld4(&W[(size_t)d * CIN + ks * 32 + g * 8 + 4]);
            float vv[8] = {a.x, a.y, a.z, a.w, bq.x, bq.y, bq.z, bq.w};
            bf16x8 h8, l8;
            #pragma unroll
            for (int e = 0; e < 8; ++e) {
                unsigned short hh = f2bf(vv[e]);
                h8[e] = (short)hh;
                l8[e] = (short)f2bf(vv[e] - bf2f(hh));
            }
            Whi[ks] = h8; Wlo[ks] = l8;
        }
    }
    constexpr int TN4 = TN / 4;
    constexpr int NF = (TN * CIN) / 1024;
    #pragma unroll
    for (int f = 0; f < NF; ++f) {
        int idx = tid + 256 * f;
        int c = idx / TN4;
        int n = (idx % TN4) * 4;
        float4 xv = ld4(&X[((size_t)(b * CIN + c)) * NPTS + n0 + n]);
        float vv[4] = {xv.x, xv.y, xv.z, xv.w};
        #pragma unroll
        for (int j2 = 0; j2 < 4; ++j2) {
            int nn = n + j2;
            int cp = (c + nn * 8) & (CIN - 1);
            unsigned short hh = f2bf(vv[j2]);
            Xhi[nn * CIN + cp] = hh;
            Xlo[nn * CIN + cp] = f2bf(vv[j2] - bf2f(hh));
        }
    }
    __syncthreads();

    f32x4 acc[FB];
    #pragma unroll
    for (int fb = 0; fb < FB; ++fb) acc[fb] = (f32x4){0.f, 0.f, 0.f, 0.f};
    #pragma unroll
    for (int ks = 0; ks < KS; ++ks) {
        #pragma unroll
        for (int fb = 0; fb < FB; ++fb) {
            int n = nw + fb * 16 + l15;
            int cp = (ks * 32 + g * 8 + n * 8) & (CIN - 1);
            bf16x8 xh = *reinterpret_cast<bf16x8*>(&Xhi[n * CIN + cp]);
            bf16x8 xl = *reinterpret_cast<bf16x8*>(&Xlo[n * CIN + cp]);
            acc[fb] = __builtin_amdgcn_mfma_f32_16x16x32_bf16(Wlo[ks], xh, acc[fb], 0, 0, 0);
            acc[fb] = __builtin_amdgcn_mfma_f32_16x16x32_bf16(Whi[ks], xl, acc[fb], 0, 0, 0);
            acc[fb] = __builtin_amdgcn_mfma_f32_16x16x32_bf16(Whi[ks], xh, acc[fb], 0, 0, 0);
        }
    }
    const int dbase = d0 + dw + g * 4;
    float bb[4] = {0.f, 0.f, 0.f, 0.f};
    if (BIAS) {
        float4 b4 = ld4(&bias[dbase]);
        bb[0] = b4.x; bb[1] = b4.y; bb[2] = b4.z; bb[3] = b4.w;
    }
    float s1[4] = {0.f, 0.f, 0.f, 0.f};
    float s2[4] = {0.f, 0.f, 0.f, 0.f};
    #pragma unroll
    for (int fb = 0; fb < FB; ++fb) {
        int ncol = n0 + nw + fb * 16 + l15;
        if (MODE == 1) {
            unsigned short* ob = (unsigned short*)outv;
            #pragma unroll
            for (int r = 0; r < 4; ++r)
                ob[((size_t)(b * COUT + dbase + r)) * NPTS + ncol] = f2bf(acc[fb][r] + bb[r]);
        } else {
            float* ob = (float*)outv;
            #pragma unroll
            for (int r = 0; r < 4; ++r) {
                float val = acc[fb][r] + bb[r];
                ob[((size_t)(b * COUT + dbase + r)) * NPTS + ncol] = val;
                if (STATS) { s1[r] += val; s2[r] += val * val; }
            }
        }
    }
    if (STATS && MODE == 0) {
        #pragma unroll
        for (int r = 0; r < 4; ++r) {
            float a1 = s1[r], a2 = s2[r];
            a1 += __shfl_xor(a1, 1, 64);  a2 += __shfl_xor(a2, 1, 64);
            a1 += __shfl_xor(a1, 2, 64);  a2 += __shfl_xor(a2, 2, 64);
            a1 += __shfl_xor(a1, 4, 64);  a2 += __shfl_xor(a2, 4, 64);
            a1 += __shfl_xor(a1, 8, 64);  a2 += __shfl_xor(a2, 8, 64);
            if (l15 == 0) {
                int c = dbase + r;
                int slot = b * 64 + blockIdx.x;
                pout[(size_t)c * 512 + slot] = a1;
                pout[(size_t)(128 + c) * 512 + slot] = a2;
            }
        }
    }
}

// ---------------------------------------------------------------------------
// Fused q/k + v projection: one pass over h.
// ---------------------------------------------------------------------------
__global__ __launch_bounds__(256) void qkv_kernel(
        const float* __restrict__ Wqk, const float* __restrict__ Wv,
        const float* __restrict__ X, const float* __restrict__ bv,
        unsigned short* __restrict__ vb,
        unsigned short* __restrict__ qh, unsigned short* __restrict__ ql)
{
    __shared__ unsigned short Xhi[32 * 128];
    __shared__ unsigned short Xlo[32 * 128];
    const int tid = threadIdx.x;
    const int lane = tid & 63;
    const int w = tid >> 6;          // 0..3
    const int g = lane >> 4;
    const int l15 = lane & 15;
    const int b = blockIdx.z;
    const int gy = blockIdx.y;
    const int d0 = gy * 64;
    const int n0 = blockIdx.x * 32;
    const int dw = w * 16;
    const bool doqk = (gy == 0) && (w < 2);

    bf16x8 Vhi[4], Vlo[4];
    {
        const int d = d0 + dw + l15;
        #pragma unroll
        for (int ks = 0; ks < 4; ++ks) {
            float4 a = ld4(&Wv[(size_t)d * 128 + ks * 32 + g * 8]);
            float4 bq = ld4(&Wv[(size_t)d * 128 + ks * 32 + g * 8 + 4]);
            float vv[8] = {a.x, a.y, a.z, a.w, bq.x, bq.y, bq.z, bq.w};
            bf16x8 h8, l8;
            #pragma unroll
            for (int e = 0; e < 8; ++e) {
                unsigned short hh = f2bf(vv[e]);
                h8[e] = (short)hh;
                l8[e] = (short)f2bf(vv[e] - bf2f(hh));
            }
            Vhi[ks] = h8; Vlo[ks] = l8;
        }
    }
    bf16x8 Qhi[4], Qlo[4];
    if (doqk) {
        const int d = dw + l15;
        #pragma unroll
        for (int ks = 0; ks < 4; ++ks) {
            float4 a = ld4(&Wqk[(size_t)d * 128 + ks * 32 + g * 8]);
            float4 bq = ld4(&Wqk[(size_t)d * 128 + ks * 32 + g * 8 + 4]);
            float vv[8] = {a.x, a.y, a.z, a.w, bq.x, bq.y, bq.z, bq.w};
            bf16x8 h8, l8;
            #pragma unroll
            for (int e = 0; e < 8; ++e) {
                unsigned short hh = f2bf(vv[e]);
                h8[e] = (short)hh;
                l8[e] = (short)f2bf(vv[e] - bf2f(hh));
            }
            Qhi[ks] = h8; Qlo[ks] = l8;
        }
    }
    #pragma unroll
    for (int f = 0; f < 4; ++f) {
        int idx = tid + 256 * f;
        int c = idx / 8;
        int n = (idx % 8) * 4;
        float4 xv = ld4(&X[((size_t)(b * 128 + c)) * NPTS + n0 + n]);
        float vv[4] = {xv.x, xv.y, xv.z, xv.w};
        #pragma unroll
        for (int j2 = 0; j2 < 4; ++j2) {
            int nn = n + j2;
            int cp = (c + nn * 8) & 127;
            unsigned short hh = f2bf(vv[j2]);
            Xhi[nn * 128 + cp] = hh;
            Xlo[nn * 128 + cp] = f2bf(vv[j2] - bf2f(hh));
        }
    }
    __syncthreads();

    f32x4 acc[2];
    acc[0] = (f32x4){0.f, 0.f, 0.f, 0.f};
    acc[1] = (f32x4){0.f, 0.f, 0.f, 0.f};
    #pragma unroll
    for (int ks = 0; ks < 4; ++ks) {
        #pragma unroll
        for (int fb = 0; fb < 2; ++fb) {
            int n = fb * 16 + l15;
            int cp = (ks * 32 + g * 8 + n * 8) & 127;
            bf16x8 xh = *reinterpret_cast<bf16x8*>(&Xhi[n * 128 + cp]);
            bf16x8 xl = *reinterpret_cast<bf16x8*>(&Xlo[n * 128 + cp]);
            acc[fb] = __builtin_amdgcn_mfma_f32_16x16x32_bf16(Vlo[ks], xh, acc[fb], 0, 0, 0);
            acc[fb] = __builtin_amdgcn_mfma_f32_16x16x32_bf16(Vhi[ks], xl, acc[fb], 0, 0, 0);
            acc[fb] = __builtin_amdgcn_mfma_f32_16x16x32_bf16(Vhi[ks], xh, acc[fb], 0, 0, 0);
        }
    }
    {
        const int dbase = d0 + dw + g * 4;
        float4 b4 = ld4(&bv[dbase]);
        float bb[4] = {b4.x, b4.y, b4.z, b4.w};
        #pragma unroll
        for (int fb = 0; fb < 2; ++fb) {
            int ncol = n0 + fb * 16 + l15;
            #pragma unroll
            for (int r = 0; r < 4; ++r)
                vb[((size_t)(b * 128 + dbase + r)) * NPTS + ncol] = f2bf(acc[fb][r] + bb[r]);
        }
    }
    if (doqk) {
        f32x4 accq[2];
        accq[0] = (f32x4){0.f, 0.f, 0.f, 0.f};
        accq[1] = (f32x4){0.f, 0.f, 0.f, 0.f};
        #pragma unroll
        for (int ks = 0; ks < 4; ++ks) {
            #pragma unroll
            for (int fb = 0; fb < 2; ++fb) {
                int n = fb * 16 + l15;
                int cp = (ks * 32 + g * 8 + n * 8) & 127;
                bf16x8 xh = *reinterpret_cast<bf16x8*>(&Xhi[n * 128 + cp]);
                bf16x8 xl = *reinterpret_cast<bf16x8*>(&Xlo[n * 128 + cp]);
                accq[fb] = __builtin_amdgcn_mfma_f32_16x16x32_bf16(Qlo[ks], xh, accq[fb], 0, 0, 0);
                accq[fb] = __builtin_amdgcn_mfma_f32_16x16x32_bf16(Qhi[ks], xl, accq[fb], 0, 0, 0);
                accq[fb] = __builtin_amdgcn_mfma_f32_16x16x32_bf16(Qhi[ks], xh, accq[fb], 0, 0, 0);
            }
        }
        const int dq = dw + g * 4;
        #pragma unroll
        for (int fb = 0; fb < 2; ++fb) {
            int ncol = n0 + fb * 16 + l15;
            ushort4 hh, ll;
            float q0 = accq[fb][0], q1 = accq[fb][1], q2 = accq[fb][2], q3 = accq[fb][3];
            hh.x = f2bf(q0); ll.x = f2bf(q0 - bf2f(hh.x));
            hh.y = f2bf(q1); ll.y = f2bf(q1 - bf2f(hh.y));
            hh.z = f2bf(q2); ll.z = f2bf(q2 - bf2f(hh.z));
            hh.w = f2bf(q3); ll.w = f2bf(q3 - bf2f(hh.w));
            *reinterpret_cast<ushort4*>(&qh[((size_t)b * NPTS + ncol) * 32 + dq]) = hh;
            *reinterpret_cast<ushort4*>(&ql[((size_t)b * NPTS + ncol) * 32 + dq]) = ll;
        }
    }
}

// finalize: reduce 512 coalesced partials per channel -> stats
__global__ __launch_bounds__(256) void bn_finalize_kernel(
        const float* __restrict__ part, float* __restrict__ stats, int C)
{
    __shared__ float red[4];
    const int c = blockIdx.x;
    const int tid = threadIdx.x;
    float s  = part[(size_t)c * 512 + tid] + part[(size_t)c * 512 + 256 + tid];
    float s2 = part[(size_t)(128 + c) * 512 + tid] + part[(size_t)(128 + c) * 512 + 256 + tid];
    s  = blk_red_sum(s, red);
    s2 = blk_red_sum(s2, red);
    if (tid == 0) {
        const float invn = 1.f / (NBAT * NPTS);
        float mean = s * invn;
        stats[c] = mean;
        stats[C + c] = rsqrtf(s2 * invn - mean * mean + 1e-5f);
    }
}

// row softmax stats; 1-D grid 1024, b = id&7 (XCD-aligned), i0 = (id>>3)*16
__global__ __launch_bounds__(256) void rowstats_fused_kernel(
        const unsigned short* __restrict__ qThi, const unsigned short* __restrict__ qTlo,
        float* __restrict__ rowm, float* __restrict__ rowinv)
{
    __shared__ float pm[4][16];
    __shared__ float ps[4][16];
    const int lane = threadIdx.x & 63;
    const int w = threadIdx.x >> 6;
    const int b = blockIdx.x & 7;
    const int i0 = (blockIdx.x >> 3) * 16;
    const int g = lane >> 4;
    const int l15 = lane & 15;
    const int iR = i0 + l15;
    const bf16x8 bhi = *reinterpret_cast<const bf16x8*>(&qThi[((size_t)b * NPTS + iR) * 32 + g * 8]);
    const bf16x8 blo = *reinterpret_cast<const bf16x8*>(&qTlo[((size_t)b * NPTS + iR) * 32 + g * 8]);
    float m = -1e30f, s = 0.f;
    for (int t = w * 32; t < w * 32 + 32; ++t) {
        int jr = t * 16 + l15;
        const bf16x8 ahi = *reinterpret_cast<const bf16x8*>(&qThi[((size_t)b * NPTS + jr) * 32 + g * 8]);
        const bf16x8 alo = *reinterpret_cast<const bf16x8*>(&qTlo[((size_t)b * NPTS + jr) * 32 + g * 8]);
        f32x4 e4 = {0.f, 0.f, 0.f, 0.f};
        e4 = __builtin_amdgcn_mfma_f32_16x16x32_bf16(alo, bhi, e4, 0, 0, 0);
        e4 = __builtin_amdgcn_mfma_f32_16x16x32_bf16(ahi, blo, e4, 0, 0, 0);
        e4 = __builtin_amdgcn_mfma_f32_16x16x32_bf16(ahi, bhi, e4, 0, 0, 0);
        float tm = fmaxf(fmaxf(e4[0], e4[1]), fmaxf(e4[2], e4[3]));
        float nm = fmaxf(m, tm);
        s *= __expf(m - nm);
        m = nm;
        s += __expf(e4[0] - m) + __expf(e4[1] - m) + __expf(e4[2] - m) + __expf(e4[3] - m);
    }
    #pragma unroll
    for (int o = 16; o <= 32; o <<= 1) {
        float om = __shfl_xor(m, o, 64);
        float os = __shfl_xor(s, o, 64);
        float nm = fmaxf(m, om);
        s = s * __expf(m - nm) + os * __expf(om - nm);
        m = nm;
    }
    if (lane < 16) { pm[w][l15] = m; ps[w][l15] = s; }
    __syncthreads();
    if (threadIdx.x < 16) {
        float m0 = pm[0][threadIdx.x], m1 = pm[1][threadIdx.x];
        float m2 = pm[2][threadIdx.x], m3 = pm[3][threadIdx.x];
        float mf = fmaxf(fmaxf(m0, m1), fmaxf(m2, m3));
        float sf = ps[0][threadIdx.x] * __expf(m0 - mf)
                 + ps[1][threadIdx.x] * __expf(m1 - mf)
                 + ps[2][threadIdx.x] * __expf(m2 - mf)
                 + ps[3][threadIdx.x] * __expf(m3 - mf);
        rowm[(size_t)b * NPTS + i0 + threadIdx.x] = mf;
        rowinv[(size_t)b * NPTS + i0 + threadIdx.x] = 1.f / sf;
    }
}

// Fused attention; 1-D grid 512, b = id&7 (XCD-aligned), j0 = (id>>3)*32.
// Linear prefetch + padded buffers (R19 verified optimum).
__global__ __launch_bounds__(512) void attn_fused_kernel(
        const unsigned short* __restrict__ qThi, const unsigned short* __restrict__ qTlo,
        const unsigned short* __restrict__ V,
        const float* __restrict__ rowm, const float* __restrict__ rowinv,
        const float* __restrict__ H, float* __restrict__ T)
{
    __shared__ unsigned short Alds[2][128 * 64];
    __shared__ unsigned short Blds[2][32 * 64];
    __shared__ float cparts[8][16];
    const int tid = threadIdx.x;
    const int b  = blockIdx.x & 7;
    const int j0 = (blockIdx.x >> 3) * 32;
    const int lane = tid & 63;
    const int w = tid >> 6;
    const int g = lane >> 4;
    const int l15 = lane & 15;
    const int jsub = w & 1;
    const int tE = w >> 1;
    const int jl = jsub * 16 + l15;
    const int cb = (w >> 1) * 32;
    const int jb = jsub * 16;
    const int vc = tid >> 3, vslot = tid & 7;
    const int vc1 = (tid + 512) >> 3, vslot1 = (tid + 512) & 7;
    const bf16x8 bhi = *reinterpret_cast<const bf16x8*>(&qThi[((size_t)b * NPTS + j0 + jl) * 32 + g * 8]);
    const bf16x8 blo = *reinterpret_cast<const bf16x8*>(&qTlo[((size_t)b * NPTS + j0 + jl) * 32 + g * 8]);
    f32x4 acc[2];
    acc[0] = (f32x4){0.f, 0.f, 0.f, 0.f};
    acc[1] = (f32x4){0.f, 0.f, 0.f, 0.f};
    float csum = 0.f;

    // linear prefetch pointers (advance 64 elements per step)
    const unsigned short* pv0 = V + ((size_t)(b * 128 + vc)) * NPTS + vslot * 8;
    const unsigned short* pv1 = V + ((size_t)(b * 128 + vc1)) * NPTS + vslot1 * 8;
    const unsigned short* pqh = qThi + ((size_t)b * NPTS + tE * 16 + l15) * 32 + g * 8;
    const unsigned short* pql = qTlo + ((size_t)b * NPTS + tE * 16 + l15) * 32 + g * 8;
    const float* prm = rowm + (size_t)b * NPTS + tE * 16 + g * 4;
    const float* pri = rowinv + (size_t)b * NPTS + tE * 16 + g * 4;

    float4 vreg0 = ld4((const float*)pv0);
    float4 vreg1 = ld4((const float*)pv1);
    bf16x8 pahi = *reinterpret_cast<const bf16x8*>(pqh);
    bf16x8 palo = *reinterpret_cast<const bf16x8*>(pql);
    float4 pmv = ld4(prm);
    float4 psv = ld4(pri);

    int p = 0;
    for (int i0 = 0; i0 < NPTS; i0 += 64) {
        // commit prefetched V tile to Alds[p]
        {
            int sl = vslot ^ (vc & 7);
            *reinterpret_cast<float4*>(&Alds[p][vc * 64 + sl * 8]) = vreg0;
            sl = vslot1 ^ (vc1 & 7);
            *reinterpret_cast<float4*>(&Alds[p][vc1 * 64 + sl * 8]) = vreg1;
        }
        // e-compute from prefetched qT frags -> Blds[p]
        {
            f32x4 e4 = {0.f, 0.f, 0.f, 0.f};
            e4 = __builtin_amdgcn_mfma_f32_16x16x32_bf16(palo, bhi, e4, 0, 0, 0);
            e4 = __builtin_amdgcn_mfma_f32_16x16x32_bf16(pahi, blo, e4, 0, 0, 0);
            e4 = __builtin_amdgcn_mfma_f32_16x16x32_bf16(pahi, bhi, e4, 0, 0, 0);
            float p0 = __expf(e4[0] - pmv.x) * psv.x;
            float p1 = __expf(e4[1] - pmv.y) * psv.y;
            float p2 = __expf(e4[2] - pmv.z) * psv.z;
            float p3 = __expf(e4[3] - pmv.w) * psv.w;
            csum += p0 + p1 + p2 + p3;
            int il = tE * 16 + g * 4;
            int sl = (il >> 3) ^ (jl & 7);
            ull pk = (ull)f2bf(p0) | ((ull)f2bf(p1) << 16) |
                     ((ull)f2bf(p2) << 32) | ((ull)f2bf(p3) << 48);
            *reinterpret_cast<ull*>(&Blds[p][jl * 64 + sl * 8 + (il & 7)]) = pk;
        }
        // prefetch next step (linear advance; final prefetch reads pad garbage)
        {
            pv0 += 64; pv1 += 64;
            pqh += 64 * 32; pql += 64 * 32;
            prm += 64; pri += 64;
            vreg0 = ld4((const float*)pv0);
            vreg1 = ld4((const float*)pv1);
            pahi = *reinterpret_cast<const bf16x8*>(pqh);
            palo = *reinterpret_cast<const bf16x8*>(pql);
            pmv = ld4(prm);
            psv = ld4(pri);
        }
        BAR_LDS();
        // PV: 32c x 16j slice, K=64
        #pragma unroll
        for (int ks = 0; ks < 2; ++ks) {
            int j = jb + l15;
            int slb = (ks * 4 + g) ^ (j & 7);
            bf16x8 bfr = *reinterpret_cast<bf16x8*>(&Blds[p][j * 64 + slb * 8]);
            #pragma unroll
            for (int fa = 0; fa < 2; ++fa) {
                int c = cb + fa * 16 + l15;
                int sla = (ks * 4 + g) ^ (c & 7);
                bf16x8 afr = *reinterpret_cast<bf16x8*>(&Alds[p][c * 64 + sla * 8]);
                acc[fa] = __builtin_amdgcn_mfma_f32_16x16x32_bf16(afr, bfr, acc[fa], 0, 0, 0);
            }
        }
        p ^= 1;
    }
    csum += __shfl_xor(csum, 16, 64);
    csum += __shfl_xor(csum, 32, 64);
    if (lane < 16) cparts[w][l15] = csum;
    __syncthreads();
    float cs = cparts[jsub][l15] + cparts[jsub + 2][l15]
             + cparts[jsub + 4][l15] + cparts[jsub + 6][l15];
    float inv = 1.f / (1e-9f + cs);
    int jg_ = j0 + jb + l15;
    #pragma unroll
    for (int fa = 0; fa < 2; ++fa) {
        #pragma unroll
        for (int r = 0; r < 4; ++r) {
            int c = cb + fa * 16 + g * 4 + r;
            size_t base = ((size_t)(b * 128 + c)) * NPTS + jg_;
            T[base] = H[base] - acc[fa][r] * inv;
        }
    }
}

__global__ __launch_bounds__(256) void bn_apply_kernel(const float* __restrict__ X,
        const float* __restrict__ g, const float* __restrict__ beta,
        const float* __restrict__ stats, int C, float* __restrict__ out)
{
    const int bc = blockIdx.y;
    const int c = bc % C;
    const int n = blockIdx.x * 1024 + threadIdx.x * 4;
    const float mean = stats[c], is = stats[C + c];
    const float ga = g[c] * is;
    const float be = beta[c] - mean * ga;
    float4 v = ld4(&X[(size_t)bc * NPTS + n]);
    float4 o;
    o.x = fmaxf(fmaf(ga, v.x, be), 0.f);
    o.y = fmaxf(fmaf(ga, v.y, be), 0.f);
    o.z = fmaxf(fmaf(ga, v.z, be), 0.f);
    o.w = fmaxf(fmaf(ga, v.w, be), 0.f);
    st4(&out[(size_t)bc * NPTS + n], o);
}

__global__ __launch_bounds__(256) void bn_res_kernel(const float* __restrict__ Y,
        const float* __restrict__ g, const float* __restrict__ beta,
        const float* __restrict__ stats, float* __restrict__ H,
        float* __restrict__ out, int blk)
{
    const int bc = blockIdx.y;
    const int c = bc & 127;
    const int b = bc >> 7;
    const int n = blockIdx.x * 1024 + threadIdx.x * 4;
    const float mean = stats[c], is = stats[128 + c];
    const float ga = g[c] * is;
    const float be = beta[c] - mean * ga;
    float4 yv = ld4(&Y[(size_t)bc * NPTS + n]);
    float4 hv = ld4(&H[(size_t)bc * NPTS + n]);
    float4 o;
    o.x = hv.x + fmaxf(fmaf(ga, yv.x, be), 0.f);
    o.y = hv.y + fmaxf(fmaf(ga, yv.y, be), 0.f);
    o.z = hv.z + fmaxf(fmaf(ga, yv.z, be), 0.f);
    o.w = hv.w + fmaxf(fmaf(ga, yv.w, be), 0.f);
    st4(&H[(size_t)bc * NPTS + n], o);
    st4(&out[((size_t)(b * 512 + blk * 128 + c)) * NPTS + n], o);
}

extern "C" void kernel_launch(void* const* d_in, const int* in_sizes, int n_in,
                              void* d_out, int out_size, void* d_ws, size_t ws_size,
                              hipStream_t stream)
{
    const float* x   = (const float*)d_in[0];
    const float* W1  = (const float*)d_in[1];
    const float* g1  = (const float*)d_in[2];
    const float* b1  = (const float*)d_in[3];
    const float* W2  = (const float*)d_in[4];
    const float* g2  = (const float*)d_in[5];
    const float* b2  = (const float*)d_in[6];
    const float* Wqk = (const float*)d_in[7];
    const float* Wv  = (const float*)d_in[8];
    const float* bv  = (const float*)d_in[9];
    const float* Wt  = (const float*)d_in[10];
    const float* bt  = (const float*)d_in[11];
    const float* gn  = (const float*)d_in[12];
    const float* bnb = (const float*)d_in[13];
    float* out = (float*)d_out;

    float* ws = (float*)d_ws;
    size_t off = 0;
    auto alloc = [&](size_t n) { float* p = ws + off; off += n; return p; };
    float* h      = alloc((size_t)NBAT * 128 * NPTS);
    float* t      = alloc((size_t)NBAT * 128 * NPTS);
    float* y      = alloc((size_t)NBAT * 128 * NPTS);
    float* part   = alloc((size_t)2 * 128 * 512);
    float* stats  = alloc(256);
    float* rowm   = alloc((size_t)NBAT * NPTS + 128);   // +pad for linear prefetch
    float* rowinv = alloc((size_t)NBAT * NPTS + 128);   // +pad
    unsigned short* vb   = (unsigned short*)alloc((size_t)NBAT * 128 * NPTS / 2 + 2048);
    unsigned short* qThi = (unsigned short*)alloc((size_t)NBAT * NPTS * 32 / 2 + 2048);
    unsigned short* qTlo = (unsigned short*)alloc((size_t)NBAT * NPTS * 32 / 2 + 2048);

    // stem: h = relu(bn(W2 @ relu(bn(W1 @ x))))
    lin_mfma_kernel<64, 64, 64, 32, 0, false, true><<<dim3(64, 1, NBAT), 256, 0, stream>>>(
        W1, x, nullptr, y, part);
    bn_finalize_kernel<<<64, 256, 0, stream>>>(part, stats, 64);
    bn_apply_kernel<<<dim3(2, NBAT * 64), 256, 0, stream>>>(y, g1, b1, stats, 64, t);
    lin_mfma_kernel<64, 128, 64, 32, 0, false, true><<<dim3(64, 2, NBAT), 256, 0, stream>>>(
        W2, t, nullptr, y, part);
    bn_finalize_kernel<<<128, 256, 0, stream>>>(part, stats, 128);
    bn_apply_kernel<<<dim3(2, NBAT * 128), 256, 0, stream>>>(y, g2, b2, stats, 128, h);

    for (int blk = 0; blk < 4; ++blk) {
        qkv_kernel<<<dim3(64, 2, NBAT), 256, 0, stream>>>(
            Wqk + (size_t)blk * 32 * 128, Wv + (size_t)blk * 128 * 128,
            h, bv + blk * 128, vb, qThi, qTlo);
        rowstats_fused_kernel<<<1024, 256, 0, stream>>>(qThi, qTlo, rowm, rowinv);
        attn_fused_kernel<<<512, 512, 0, stream>>>(
            qThi, qTlo, vb, rowm, rowinv, h, t);
        lin_mfma_kernel<128, 128, 64, 32, 0, true, true><<<dim3(64, 2, NBAT), 256, 0, stream>>>(
            Wt + (size_t)blk * 128 * 128, t, bt + blk * 128, y, part);
        bn_finalize_kernel<<<128, 256, 0, stream>>>(part, stats, 128);
        bn_res_kernel<<<dim3(2, NBAT * 128), 256, 0, stream>>>(
            y, gn + blk * 128, bnb + blk * 128, stats, h, out, blk);
    }
}